// Round 15
// baseline (612.556 us; speedup 1.0000x reference)
//
#include <hip/hip_runtime.h>
#include <hip/hip_bf16.h>
#include <cstdint>

typedef unsigned short u16;
typedef __attribute__((ext_vector_type(8))) short short8;
typedef __attribute__((ext_vector_type(4))) float floatx4;
typedef __attribute__((ext_vector_type(4))) int intx4;

#define PA_TOTAL 13696   // sum of per-level pixel counts, each padded to 128
#define CCH 256
#define KTOT 2304        // 9 taps * 256 ic

struct Tables {
  int H[5], W[5], P[5], base[5], tile0[5];
  int lb[5], bb[5], cb[5];   // d_out offsets: logits, bbox, centerness per level
};
struct FeatPtrs { const float* f[5]; };
struct ConvArgs {
  const u16* X[2];      // per-tower input activations
  const u16* Wt[2];     // per-tower weight matrices for this stage
  u16* outB[2];         // per-tower conv output (bf16 NHWC)
  float* stats;         // [tower][ (b*5+lvl)*32+g ][2]  -> tower stride 640 floats
  float* dout;
  const float* biasCls; const float* biasCtr; const float* biasBox; const float* scales;
};
struct ReorderArgs {
  const float* cls_w; const float* box_w; const float* pcls_w; const float* ctr_w; const float* pbox_w;
  u16* wrCls; u16* wrBox; u16* wrPCls; u16* wrPBox;
};

__device__ __forceinline__ u16 f2bf(float f) {
  union { float f; unsigned u; } v; v.f = f;
  unsigned r = v.u + 0x7fffu + ((v.u >> 16) & 1u);   // RNE
  return (u16)(r >> 16);
}
__device__ __forceinline__ float bf2f(u16 h) {
  union { unsigned u; float f; } v; v.u = ((unsigned)h) << 16;
  return v.f;
}

// async global->LDS: 16B per lane, dest = wave-uniform base + lane*16.
__device__ __forceinline__ void gload16(const void* g, void* l) {
  __builtin_amdgcn_global_load_lds(
      (const __attribute__((address_space(1))) void*)g,
      (__attribute__((address_space(3))) void*)l, 16, 0, 0);
}

// ---- ALL weight reordering in ONE launch (R8 consolidation, kept).
__global__ void reorder_all(ReorderArgs ra) {
  __shared__ float row[KTOT];
  const int r = blockIdx.x;
  const float* s;
  u16* o;
  if (r < 1024)      { s = ra.cls_w  + (size_t)r * KTOT;          o = ra.wrCls  + (size_t)r * KTOT; }
  else if (r < 2048) { int q = r - 1024; s = ra.box_w  + (size_t)q * KTOT; o = ra.wrBox  + (size_t)q * KTOT; }
  else if (r < 2068) { int q = r - 2048; s = ra.pcls_w + (size_t)q * KTOT; o = ra.wrPCls + (size_t)q * KTOT; }
  else if (r == 2068){ s = ra.ctr_w;                               o = ra.wrPCls + (size_t)20 * KTOT; }
  else if (r < 2073) { int q = r - 2069; s = ra.pbox_w + (size_t)q * KTOT; o = ra.wrPBox + (size_t)q * KTOT; }
  else if (r < 2084) {
    u16* oz = ra.wrPCls + (size_t)(21 + (r - 2073)) * KTOT;
#pragma unroll
    for (int j = 0; j < 9; ++j) oz[threadIdx.x + j * 256] = 0;
    return;
  } else {
    u16* oz = ra.wrPBox + (size_t)(4 + (r - 2084)) * KTOT;
#pragma unroll
    for (int j = 0; j < 9; ++j) oz[threadIdx.x + j * 256] = 0;
    return;
  }
#pragma unroll
  for (int j = 0; j < 9; ++j) row[threadIdx.x + j * 256] = s[threadIdx.x + j * 256];
  __syncthreads();
#pragma unroll
  for (int j = 0; j < 9; ++j) {
    int k = threadIdx.x + j * 256;
    o[k] = f2bf(row[(k & 255) * 9 + (k >> 8)]);
  }
}

// ---- inputs NCHW f32 -> NHWC bf16, 32x32 LDS transpose (coalesced both sides)
// grid: (PA_TOTAL/32, 8, 2)  block 256. Pixel-padding rows written as ZERO
// (they are the conv staging's halo redirect target).
__global__ void convert_inputs(FeatPtrs fp, u16* __restrict__ out, Tables tb) {
  __shared__ float tile[32][33];
  const int pt = blockIdx.x, c32 = blockIdx.y, b = blockIdx.z;
  const int p0 = pt * 32;
  int lvl = 0;
#pragma unroll
  for (int i = 1; i < 5; ++i) if (p0 >= tb.base[i]) lvl = i;
  const int P = tb.P[lvl];
  const int pl0 = p0 - tb.base[lvl];
  const int r = threadIdx.x >> 5, col = threadIdx.x & 31;
  const float* src = fp.f[lvl] + ((size_t)b * CCH + c32 * 32) * P;
#pragma unroll
  for (int i = 0; i < 4; ++i) {
    int crow = r + i * 8;
    int pl = pl0 + col;
    tile[crow][col] = (pl < P) ? src[(size_t)crow * P + pl] : 0.f;
  }
  __syncthreads();
#pragma unroll
  for (int i = 0; i < 4; ++i) {
    int px = r + i * 8;
    out[((size_t)b * PA_TOTAL + p0 + px) * CCH + c32 * 32 + col] = f2bf(tile[col][px]);
  }
}

// ---- TOWER conv3x3: implicit-GEMM, bf16 MFMA 16x16x32, 128oc x 128px tile,
// DMA staging, LDS DOUBLE-BUFFER AT CONSTANT 32KB (BK=32). Session-best
// verified configuration (R13: total 606us; conv 114us, MfmaUtil 23.5,
// VGPR 72, no spill). Per step s: [s_barrier A] (prev readers of buf^1 done)
// -> issue 4 gloads for s+1 into buf^1 -> [vmcnt(4) + s_barrier B] (s-loads
// landed block-wide; s+1-loads STAY IN FLIGHT a full step) -> 16 MFMA on
// buf[s&1]. Loads consumed a full step after issue -> latency off the
// critical path. BK=32 swizzle: LDS slot (row,c) holds global 16B chunk
// c ^ ((row^(row>>2))&3), pre-folded into per-lane GLOBAL offset (qsw2);
// LDS dest linear lane*16 (rule 21). Halo-invalid lanes redirect source to
// the level's zero pixel-padding rows. grid (107,2,4) = 856 = 8*107.
__global__ __launch_bounds__(256) void conv_tower(ConvArgs a, Tables tb) {
  const int L = blockIdx.x + 107 * (blockIdx.y + 2 * blockIdx.z);
  const int xcd = L & 7, slot = L >> 3;
  const int tower = xcd >> 2, mt = (xcd >> 1) & 1, b = xcd & 1, t = slot;
  int lvl = 0;
#pragma unroll
  for (int i = 1; i < 5; ++i) if (t >= tb.tile0[i]) lvl = i;
  const int H = tb.H[lvl], W = tb.W[lvl], P = tb.P[lvl], base = tb.base[lvl];
  const int n0 = (t - tb.tile0[lvl]) * 128;

  const int tid = threadIdx.x;
  const int lane = tid & 63, wv = tid >> 6;
  const int wm = wv >> 1, wn = wv & 1;

  // 2 buffers x (X 8192B + W 8192B) = 32KB, one contiguous symbol.
  __shared__ u16 ldsAll[2 * 8192];

  const char* Xb = (const char*)(a.X[tower] + ((size_t)b * PA_TOTAL + base) * CCH);
  const char* Wb = (const char*)(a.Wt[tower] + (size_t)(mt * 128) * KTOT);

  // BK=32 staging: gload g (=wv+4k) covers tile rows 16g..16g+15; lane l ->
  // row = 16g + (l>>2), chunk = l&3; fetched global chunk = chunk ^ swz(row),
  // swz(row) = (row ^ (row>>2)) & 3 = ((l>>2) ^ (l>>4)) & 3 (16g drops out).
  const int qsw2 = (((lane & 3) ^ ((lane >> 2) & 3) ^ ((lane >> 4) & 3))) * 16;
  int xoffG[2];                     // per-lane global byte offsets (row term)
  unsigned mask9[2];
  int xl[2];                        // wave-uniform LDS byte bases (X and W share)
#pragma unroll
  for (int k = 0; k < 2; ++k) {
    const int g = wv + 4 * k;
    const int prow = n0 + 16 * g + (lane >> 2);
    int rr = prow / W, cc = prow - rr * W;
    unsigned m = 0;
#pragma unroll
    for (int tap = 0; tap < 9; ++tap) {
      const int dh = tap / 3 - 1, dw = tap % 3 - 1;
      bool v = ((unsigned)(rr + dh) < (unsigned)H) & ((unsigned)(cc + dw) < (unsigned)W);
      m |= ((unsigned)v) << tap;
    }
    mask9[k] = m;
    xoffG[k] = prow * 512 + qsw2;
    xl[k] = g * 1024;
  }
  const int padbase = P * 512 + qsw2;    // zero pixel-padding row (halo target)
  int woffG[2];
#pragma unroll
  for (int k = 0; k < 2; ++k) {
    const int wrow = 16 * (wv + 4 * k) + (lane >> 2);
    woffG[k] = wrow * (KTOT * 2) + qsw2;
  }

  // readers: af row = wm*64+i*16+arow (W region), bv row = wn*64+j*16+arow (X).
  // reader chunk = kq ^ swz(row); row base mult of 16 -> swz depends on arow only.
  const int arow = lane & 15, kq = lane >> 4;
  const int csw0 = ((kq ^ (arow & 3) ^ ((arow >> 2) & 3))) * 16;   // bytes
  int rbA[4], rbX[4];
#pragma unroll
  for (int i = 0; i < 4; ++i) {
    rbA[i] = (wm * 64 + i * 16 + arow) * 64 + csw0;
    rbX[i] = (wn * 64 + i * 16 + arow) * 64 + csw0;
  }

  floatx4 acc[4][4];
#pragma unroll
  for (int i = 0; i < 4; ++i)
#pragma unroll
    for (int j = 0; j < 4; ++j) acc[i][j] = (floatx4)0.f;

  // prologue: issue step 0 (tap 0, icb2 0) into buffer 0
  {
    const int doff0 = (-W - 1) * 512;
#pragma unroll
    for (int k = 0; k < 2; ++k) {
      const int off = (mask9[k] & 1u) ? (xoffG[k] + doff0) : padbase;
      gload16(Xb + off, (char*)ldsAll + xl[k]);
    }
#pragma unroll
    for (int k = 0; k < 2; ++k)
      gload16(Wb + woffG[k], (char*)ldsAll + 8192 + xl[k]);
  }

  int pb = 0;
  // K-loop: icb2 (8 x 32ic) outer, taps inner. 72 steps, dbuf ping-pong.
#pragma unroll 1
  for (int icb2 = 0; icb2 < 8; ++icb2) {
#pragma unroll
    for (int tap = 0; tap < 9; ++tap) {
      // barrier A: all waves done READING buf^1 (their MFMA(s-1) ds_reads
      // completed before their barrier A; lgkm deps enforced by compiler).
      asm volatile("s_barrier" ::: "memory");
      if (!(icb2 == 7 && tap == 8)) {
        const int ntap = (tap == 8) ? 0 : tap + 1;
        const int nic  = (tap == 8) ? icb2 + 1 : icb2;
        const int ndh = ntap / 3;
        const int ndoff = ((ndh - 1) * W + (ntap - 3 * ndh - 1)) * 512;
        const int nslice = nic * 64;
        char* bufN = (char*)ldsAll + (pb ^ 1) * 16384;
#pragma unroll
        for (int k = 0; k < 2; ++k) {
          const int off = ((((mask9[k] >> ntap) & 1u) ? (xoffG[k] + ndoff) : padbase)) + nslice;
          gload16(Xb + off, bufN + xl[k]);
        }
        const int nko = ntap * 512 + nslice;
#pragma unroll
        for (int k = 0; k < 2; ++k)
          gload16(Wb + woffG[k] + nko, bufN + 8192 + xl[k]);
        // barrier B: wait the 4 STEP-OLD loads (4 newer stay in flight).
        asm volatile("s_waitcnt vmcnt(4)\n\ts_barrier" ::: "memory");
      } else {
        asm volatile("s_waitcnt vmcnt(0)\n\ts_barrier" ::: "memory");
      }
      const char* bufc = (const char*)ldsAll + pb * 16384;
      __builtin_amdgcn_s_setprio(1);
      short8 af[4], bv[4];
#pragma unroll
      for (int i = 0; i < 4; ++i) af[i] = *(const short8*)(bufc + 8192 + rbA[i]);
#pragma unroll
      for (int j = 0; j < 4; ++j) bv[j] = *(const short8*)(bufc + rbX[j]);
#pragma unroll
      for (int i = 0; i < 4; ++i)
#pragma unroll
        for (int j = 0; j < 4; ++j)
          acc[i][j] = __builtin_amdgcn_mfma_f32_16x16x32_bf16(af[i], bv[j], acc[i][j], 0, 0, 0);
      __builtin_amdgcn_s_setprio(0);
      pb ^= 1;
    }
  }

  // epilogue; D[m=(lane>>4)*4+r][n=lane&15]
  const int quad = lane >> 4, col = lane & 15;
  u16* convB = a.outB[tower];
  float s[4] = {0.f, 0.f, 0.f, 0.f}, ss[4] = {0.f, 0.f, 0.f, 0.f};
#pragma unroll
  for (int j = 0; j < 4; ++j) {
    int pl = n0 + wn * 64 + j * 16 + col;
    bool valid = pl < P;
    u16* dst = convB + ((size_t)b * PA_TOTAL + base + pl) * CCH + mt * 128 + wm * 64 + quad * 4;
#pragma unroll
    for (int i = 0; i < 4; ++i) {
      ushort4 hv;
#pragma unroll
      for (int r = 0; r < 4; ++r) {
        u16 hh = f2bf(acc[i][j][r]);
        ((u16*)&hv)[r] = hh;
        float vr = bf2f(hh);                    // accumulate ROUNDED value -> GN self-consistent
        if (valid) { s[i] += vr; ss[i] += vr * vr; }
      }
      if (valid) *(ushort4*)(dst + i * 16) = hv;
    }
  }
#pragma unroll
  for (int i = 0; i < 4; ++i) {
#pragma unroll
    for (int off = 16; off >= 1; off >>= 1) {
      s[i] += __shfl_down(s[i], off, 64);
      ss[i] += __shfl_down(ss[i], off, 64);
    }
  }
  if ((lane & 31) == 0) {
    int half = lane >> 5;
#pragma unroll
    for (int i = 0; i < 4; ++i) {
      float* st = a.stats + tower * 640 +
                  ((size_t)((b * 5 + lvl) * 32 + mt * 16 + wm * 8 + i * 2 + half)) * 2;
      atomicAdd(st, s[i]);
      atomicAdd(st + 1, ss[i]);
    }
  }
}

// ---- PRED convs (R12's proven MODE 1 body, unchanged): 32oc x 128px tiles,
// single-buffer DMA staging, vmcnt(0) per step. grid (108,2,2).
__global__ __launch_bounds__(256) void conv_pred(ConvArgs a, Tables tb) {
  constexpr int NI = 1;
  constexpr int WROWS = 32;
  const int L = blockIdx.x + 108 * (blockIdx.y + 2 * blockIdx.z);
  const int xcd = L & 7, slot = L >> 3;
  const int tower = xcd >> 2, b = (xcd >> 1) & 1;
  const int t = slot * 2 + (xcd & 1);
  if (t >= 107) return;
  int lvl = 0;
#pragma unroll
  for (int i = 1; i < 5; ++i) if (t >= tb.tile0[i]) lvl = i;
  const int H = tb.H[lvl], W = tb.W[lvl], P = tb.P[lvl], base = tb.base[lvl];
  const int n0 = (t - tb.tile0[lvl]) * 128;

  const int tid = threadIdx.x;
  const int lane = tid & 63, wv = tid >> 6;
  const int wm = wv >> 1, wn = wv & 1;

  __shared__ u16 ldsAll[128 * 64 + WROWS * 64];
  u16* ldsX = ldsAll;
  u16* ldsW = ldsAll + 128 * 64;

  const char* Xb = (const char*)(a.X[tower] + ((size_t)b * PA_TOTAL + base) * CCH);
  const char* Wb = (const char*)(a.Wt[tower]);

  const int qsw2 = ((lane & 7) ^ (lane >> 3)) * 16;
  int xoffG[4];
  unsigned mask9[4];
  int xlds[4];
#pragma unroll
  for (int t4 = 0; t4 < 4; ++t4) {
    int row = (t4 * 4 + wv) * 8 + (lane >> 3);
    int prow = n0 + row;
    int rr = prow / W, cc = prow - rr * W;
    unsigned m = 0;
#pragma unroll
    for (int tap = 0; tap < 9; ++tap) {
      const int dh = tap / 3 - 1, dw = tap % 3 - 1;
      bool v = ((unsigned)(rr + dh) < (unsigned)H) & ((unsigned)(cc + dw) < (unsigned)W);
      m |= ((unsigned)v) << tap;
    }
    mask9[t4] = m;
    xoffG[t4] = prow * (CCH * 2) + qsw2;
    xlds[t4] = (t4 * 4 + wv) * 1024;
  }
  const int padoff = P * (CCH * 2) + qsw2;
  int woffG[NI];
  int wlds[NI];
#pragma unroll
  for (int e = 0; e < NI; ++e) {
    int wrow = wv * 8 + (lane >> 3);
    woffG[e] = wrow * (KTOT * 2) + qsw2;
    wlds[e] = 16384 + wv * 1024;
  }

  const int arow = lane & 15, rsw = lane & 7, kq0 = lane >> 4;
  const int csw0 = (kq0 ^ rsw) * 8;
  int aoff[NI], boff[4];
#pragma unroll
  for (int i = 0; i < NI; ++i) aoff[i] = (wm * 16 + arow) * 64 + csw0;
#pragma unroll
  for (int i = 0; i < 4; ++i) boff[i] = (wn * 64 + i * 16 + arow) * 64 + csw0;

  floatx4 acc[NI][4];
#pragma unroll
  for (int i = 0; i < NI; ++i)
#pragma unroll
    for (int j = 0; j < 4; ++j) acc[i][j] = (floatx4)0.f;

#pragma unroll 1
  for (int icb = 0; icb < 4; ++icb) {
#pragma unroll
    for (int tap = 0; tap < 9; ++tap) {
      __syncthreads();
      const int ko = (tap * 256 + icb * 64) * 2;
      const int dh = tap / 3 - 1, dw = tap % 3 - 1;
      const int doff = (dh * W + dw) * (CCH * 2) + icb * 128;
#pragma unroll
      for (int t4 = 0; t4 < 4; ++t4) {
        const int off = ((mask9[t4] >> tap) & 1u) ? (xoffG[t4] + doff) : padoff;
        gload16(Xb + off, (char*)ldsAll + xlds[t4]);
      }
#pragma unroll
      for (int e = 0; e < NI; ++e)
        gload16(Wb + woffG[e] + ko, (char*)ldsAll + wlds[e]);
      asm volatile("s_waitcnt vmcnt(0) lgkmcnt(0)\n\ts_barrier" ::: "memory");
      __builtin_amdgcn_s_setprio(1);
#pragma unroll
      for (int h = 0; h < 2; ++h) {
        const int hx = h * 32;
        short8 af[NI], bv[4];
#pragma unroll
        for (int i = 0; i < NI; ++i) af[i] = *(const short8*)(ldsW + (aoff[i] ^ hx));
#pragma unroll
        for (int j = 0; j < 4; ++j) bv[j] = *(const short8*)(ldsX + (boff[j] ^ hx));
#pragma unroll
        for (int i = 0; i < NI; ++i)
#pragma unroll
          for (int j = 0; j < 4; ++j)
            acc[i][j] = __builtin_amdgcn_mfma_f32_16x16x32_bf16(af[i], bv[j], acc[i][j], 0, 0, 0);
      }
      __builtin_amdgcn_s_setprio(0);
    }
  }

  const int quad = lane >> 4, col = lane & 15;
  float* dout = a.dout;
  if (tower == 0) {
#pragma unroll
    for (int j = 0; j < 4; ++j) {
      int pl = n0 + wn * 64 + j * 16 + col;
      if (pl >= P) continue;
      int ocb = wm * 16 + quad * 4;
#pragma unroll
      for (int r = 0; r < 4; ++r) {
        int oc = ocb + r;
        float v = acc[0][j][r];
        if (oc < 20)       dout[tb.lb[lvl] + ((size_t)b * 20 + oc) * P + pl] = v + a.biasCls[oc];
        else if (oc == 20) dout[tb.cb[lvl] + (size_t)b * P + pl] = v + a.biasCtr[0];
      }
    }
  } else {
    float sc = a.scales[lvl];
#pragma unroll
    for (int j = 0; j < 4; ++j) {
      int pl = n0 + wn * 64 + j * 16 + col;
      if (pl >= P) continue;
      int ocb = wm * 16 + quad * 4;
#pragma unroll
      for (int r = 0; r < 4; ++r) {
        int oc = ocb + r;
        if (oc < 4)
          dout[tb.bb[lvl] + ((size_t)b * 4 + oc) * P + pl] = expf((acc[0][j][r] + a.biasBox[oc]) * sc);
      }
    }
  }
}

// ---- GroupNorm pass 2: normalize + affine + ReLU, bf16 -> bf16, coalesced; both towers.
// grid (3424, 2): y = tower. Pixel-padding rows ZEROED (conv halo redirect target).
__global__ void gn_norm(const u16* __restrict__ c0, const u16* __restrict__ c1,
                        const float* __restrict__ stats,
                        const float* __restrict__ g0, const float* __restrict__ b0,
                        const float* __restrict__ g1, const float* __restrict__ b1,
                        u16* __restrict__ a0, u16* __restrict__ a1, Tables tb) {
  const int tower = blockIdx.y;
  const u16* convB = tower ? c1 : c0;
  const float* gamma = tower ? g1 : g0;
  const float* beta = tower ? b1 : b0;
  u16* act = tower ? a1 : a0;
  int idx = blockIdx.x * 256 + threadIdx.x;
  int c8 = idx & 31;                 // == group index
  int rest = idx >> 5;
  int p = rest % PA_TOTAL;
  int b = rest / PA_TOTAL;
  int lvl = 0;
#pragma unroll
  for (int i = 1; i < 5; ++i) if (p >= tb.base[i]) lvl = i;
  if (p - tb.base[lvl] >= tb.P[lvl]) {
    short8 z = (short8)(short)0;
    *(short8*)(act + ((size_t)b * PA_TOTAL + p) * CCH + c8 * 8) = z;
    return;
  }
  const float* st = stats + tower * 640 + ((size_t)((b * 5 + lvl) * 32 + c8)) * 2;
  float cnt = 8.f * (float)tb.P[lvl];
  float mean = st[0] / cnt;
  float var = st[1] / cnt - mean * mean;
  float inv = rsqrtf(var + 1e-5f);
  const short8 x = *(const short8*)(convB + ((size_t)b * PA_TOTAL + p) * CCH + c8 * 8);
  short8 o;
#pragma unroll
  for (int j = 0; j < 8; ++j) {
    float v = bf2f((u16)x[j]);
    float y = (v - mean) * inv * gamma[c8 * 8 + j] + beta[c8 * 8 + j];
    y = fmaxf(y, 0.f);
    o[j] = (short)f2bf(y);
  }
  *(short8*)(act + ((size_t)b * PA_TOTAL + p) * CCH + c8 * 8) = o;
}

extern "C" void kernel_launch(void* const* d_in, const int* in_sizes, int n_in,
                              void* d_out, int out_size, void* d_ws, size_t ws_size,
                              hipStream_t stream) {
  const float* feat[5];
  for (int i = 0; i < 5; ++i) feat[i] = (const float*)d_in[i];
  const float* cls_tw_w  = (const float*)d_in[5];
  const float* cls_tw_g  = (const float*)d_in[6];
  const float* cls_tw_b  = (const float*)d_in[7];
  const float* box_tw_w  = (const float*)d_in[8];
  const float* box_tw_g  = (const float*)d_in[9];
  const float* box_tw_b  = (const float*)d_in[10];
  const float* cls_pred_w = (const float*)d_in[11];
  const float* cls_pred_b = (const float*)d_in[12];
  const float* box_pred_w = (const float*)d_in[13];
  const float* box_pred_b = (const float*)d_in[14];
  const float* ctr_pred_w = (const float*)d_in[15];
  const float* ctr_pred_b = (const float*)d_in[16];
  const float* scales     = (const float*)d_in[17];
  float* out = (float*)d_out;

  char* ws = (char*)d_ws;
  float* statsAll = (float*)(ws);                    // 4 stages x 1280 floats = 20480 B
  u16*   WrCls  = (u16*)(ws + 24576);                // 1024 x 2304 bf16
  u16*   WrBox  = (u16*)(ws + 24576 + 4718592);
  u16*   WrPCls = (u16*)(ws + 24576 + 2 * 4718592);              // 32 x 2304 (21 used)
  u16*   WrPBox = (u16*)(ws + 24576 + 2 * 4718592 + 147456);     // 32 x 2304 (4 used)
  u16*   bufIn   = (u16*)(ws + 10625024);
  u16*   bufAct0 = (u16*)(ws + 10625024 + 1 * (size_t)14024704);
  u16*   bufAct1 = (u16*)(ws + 10625024 + 2 * (size_t)14024704);
  u16*   bufCv0  = (u16*)(ws + 10625024 + 3 * (size_t)14024704);
  u16*   bufCv1  = (u16*)(ws + 10625024 + 4 * (size_t)14024704);

  // 128-px tiling: tile0 {0,79,99,104,106}, 107 tiles
  Tables tb = { {100,50,25,13,7}, {100,50,25,13,7}, {10000,2500,625,169,49},
                {0,10112,12672,13312,13568}, {0,79,99,104,106},
                {0,400000,500000,525000,531760},
                {533720,613720,633720,638720,640072},
                {640464,660464,665464,666714,667052} };

  // one upfront memset for all 4 stages' stats
  hipMemsetAsync(statsAll, 0, 20480, stream);

  ReorderArgs ra = { cls_tw_w, box_tw_w, cls_pred_w, ctr_pred_w, box_pred_w,
                     WrCls, WrBox, WrPCls, WrPBox };
  reorder_all<<<2112, 256, 0, stream>>>(ra);

  FeatPtrs fp = {{feat[0], feat[1], feat[2], feat[3], feat[4]}};
  convert_inputs<<<dim3(PA_TOTAL / 32, 8, 2), 256, 0, stream>>>(fp, bufIn, tb);

  ConvArgs a;
  a.dout = out;
  a.biasCls = cls_pred_b; a.biasCtr = ctr_pred_b; a.biasBox = box_pred_b; a.scales = scales;
  a.outB[0] = bufCv0; a.outB[1] = bufCv1;

  for (int s = 0; s < 4; ++s) {
    a.X[0] = (s == 0) ? bufIn : bufAct0;
    a.X[1] = (s == 0) ? bufIn : bufAct1;
    a.Wt[0] = WrCls + (size_t)s * 256 * KTOT;
    a.Wt[1] = WrBox + (size_t)s * 256 * KTOT;
    a.stats = statsAll + (size_t)s * 1280;
    conv_tower<<<dim3(107, 2, 4), 256, 0, stream>>>(a, tb);
    gn_norm<<<dim3(3424, 2), 256, 0, stream>>>(bufCv0, bufCv1, a.stats,
                                               cls_tw_g + s * 256, cls_tw_b + s * 256,
                                               box_tw_g + s * 256, box_tw_b + s * 256,
                                               bufAct0, bufAct1, tb);
  }
  a.X[0] = bufAct0; a.X[1] = bufAct1;
  a.Wt[0] = WrPCls; a.Wt[1] = WrPBox;
  conv_pred<<<dim3(108, 2, 2), 256, 0, stream>>>(a, tb);
}

// Round 16
// 580.212 us; speedup vs baseline: 1.0557x; 1.0557x over previous
//
#include <hip/hip_runtime.h>
#include <hip/hip_bf16.h>
#include <cstdint>

typedef unsigned short u16;
typedef __attribute__((ext_vector_type(8))) short short8;
typedef __attribute__((ext_vector_type(4))) float floatx4;
typedef __attribute__((ext_vector_type(4))) int intx4;

#define PA_TOTAL 13696   // sum of per-level pixel counts, each padded to 128
#define CCH 256
#define KTOT 2304        // 9 taps * 256 ic

struct Tables {
  int H[5], W[5], P[5], base[5], tile0[5];
  int lb[5], bb[5], cb[5];   // d_out offsets: logits, bbox, centerness per level
};
struct FeatPtrs { const float* f[5]; };
struct ConvArgs {
  const u16* X[2];      // per-tower input activations
  const u16* Wt[2];     // per-tower weight matrices for this stage
  u16* outB[2];         // per-tower conv output (bf16 NHWC)
  float* stats;         // [tower][ (b*5+lvl)*32+g ][2]  -> tower stride 640 floats
  float* dout;
  const float* biasCls; const float* biasCtr; const float* biasBox; const float* scales;
};
struct ReorderArgs {
  const float* cls_w; const float* box_w; const float* pcls_w; const float* ctr_w; const float* pbox_w;
  u16* wrCls; u16* wrBox; u16* wrPCls; u16* wrPBox;
};

__device__ __forceinline__ u16 f2bf(float f) {
  union { float f; unsigned u; } v; v.f = f;
  unsigned r = v.u + 0x7fffu + ((v.u >> 16) & 1u);   // RNE
  return (u16)(r >> 16);
}
__device__ __forceinline__ float bf2f(u16 h) {
  union { unsigned u; float f; } v; v.u = ((unsigned)h) << 16;
  return v.f;
}

// async global->LDS: 16B per lane, dest = wave-uniform base + lane*16.
__device__ __forceinline__ void gload16(const void* g, void* l) {
  __builtin_amdgcn_global_load_lds(
      (const __attribute__((address_space(1))) void*)g,
      (__attribute__((address_space(3))) void*)l, 16, 0, 0);
}

// ---- ALL weight reordering in ONE launch (R8 consolidation, kept).
__global__ void reorder_all(ReorderArgs ra) {
  __shared__ float row[KTOT];
  const int r = blockIdx.x;
  const float* s;
  u16* o;
  if (r < 1024)      { s = ra.cls_w  + (size_t)r * KTOT;          o = ra.wrCls  + (size_t)r * KTOT; }
  else if (r < 2048) { int q = r - 1024; s = ra.box_w  + (size_t)q * KTOT; o = ra.wrBox  + (size_t)q * KTOT; }
  else if (r < 2068) { int q = r - 2048; s = ra.pcls_w + (size_t)q * KTOT; o = ra.wrPCls + (size_t)q * KTOT; }
  else if (r == 2068){ s = ra.ctr_w;                               o = ra.wrPCls + (size_t)20 * KTOT; }
  else if (r < 2073) { int q = r - 2069; s = ra.pbox_w + (size_t)q * KTOT; o = ra.wrPBox + (size_t)q * KTOT; }
  else if (r < 2084) {
    u16* oz = ra.wrPCls + (size_t)(21 + (r - 2073)) * KTOT;
#pragma unroll
    for (int j = 0; j < 9; ++j) oz[threadIdx.x + j * 256] = 0;
    return;
  } else {
    u16* oz = ra.wrPBox + (size_t)(4 + (r - 2084)) * KTOT;
#pragma unroll
    for (int j = 0; j < 9; ++j) oz[threadIdx.x + j * 256] = 0;
    return;
  }
#pragma unroll
  for (int j = 0; j < 9; ++j) row[threadIdx.x + j * 256] = s[threadIdx.x + j * 256];
  __syncthreads();
#pragma unroll
  for (int j = 0; j < 9; ++j) {
    int k = threadIdx.x + j * 256;
    o[k] = f2bf(row[(k & 255) * 9 + (k >> 8)]);
  }
}

// ---- inputs NCHW f32 -> NHWC bf16, 32x32 LDS transpose (coalesced both sides)
// grid: (PA_TOTAL/32, 8, 2)  block 256. Pixel-padding rows written as ZERO
// (they are the conv staging's halo redirect target).
__global__ void convert_inputs(FeatPtrs fp, u16* __restrict__ out, Tables tb) {
  __shared__ float tile[32][33];
  const int pt = blockIdx.x, c32 = blockIdx.y, b = blockIdx.z;
  const int p0 = pt * 32;
  int lvl = 0;
#pragma unroll
  for (int i = 1; i < 5; ++i) if (p0 >= tb.base[i]) lvl = i;
  const int P = tb.P[lvl];
  const int pl0 = p0 - tb.base[lvl];
  const int r = threadIdx.x >> 5, col = threadIdx.x & 31;
  const float* src = fp.f[lvl] + ((size_t)b * CCH + c32 * 32) * P;
#pragma unroll
  for (int i = 0; i < 4; ++i) {
    int crow = r + i * 8;
    int pl = pl0 + col;
    tile[crow][col] = (pl < P) ? src[(size_t)crow * P + pl] : 0.f;
  }
  __syncthreads();
#pragma unroll
  for (int i = 0; i < 4; ++i) {
    int px = r + i * 8;
    out[((size_t)b * PA_TOTAL + p0 + px) * CCH + c32 * 32 + col] = f2bf(tile[col][px]);
  }
}

// ---- TOWER conv3x3: 8-WAVE (512-thread) blocks, FULL 256oc x 128px tile
// (mt merged), single-buffer DMA staging with the VERIFIED R12 protocol
// (sync -> gloads -> vmcnt(0)+barrier -> MFMA). Ledger rationale: every
// variant moving the same global->LDS volume at the same resident-wave count
// lands ~114-119us; to win, cut requests at CONSTANT waves. Merging mt does
// exactly that: X staged ONCE per (tower,b,t) serves all 256 oc (X DMA
// halves; total staged bytes 986->740 MB/dispatch, -25%), barrier-groups
// halve, waves/CU unchanged (grid 428 x 8 waves = 13.4/CU; 48KB LDS ->
// 3-block capacity >= 1.67 resident -> NO occupancy tail). Per-wave compute
// body is bit-identical math to R12 (BK=64 XOR swizzle, 4 af + 4 bv
// ds_read_b128 per h, 32 MFMA/step). Wave grid: wm=wv>>1 in 0..3 (64-oc
// block), wn=wv&1 (64-px block). Halo-invalid lanes redirect source to the
// level's zero pixel-padding rows. grid (107,2,2): x=t, y=b, z=tower.
__global__ __launch_bounds__(512) void conv_tower(ConvArgs a, Tables tb) {
  const int t = blockIdx.x, b = blockIdx.y, tower = blockIdx.z;
  int lvl = 0;
#pragma unroll
  for (int i = 1; i < 5; ++i) if (t >= tb.tile0[i]) lvl = i;
  const int H = tb.H[lvl], W = tb.W[lvl], P = tb.P[lvl], base = tb.base[lvl];
  const int n0 = (t - tb.tile0[lvl]) * 128;

  const int tid = threadIdx.x;
  const int lane = tid & 63, wv = tid >> 6;          // wv 0..7
  const int wm = wv >> 1, wn = wv & 1;               // 4 oc-blocks x 2 px-blocks

  // ONE contiguous LDS image: X [128px][64ic] 16KB at 0, W [256oc][64ic] 32KB after.
  __shared__ u16 ldsAll[8192 + 16384];               // 48KB
  u16* ldsX = ldsAll;
  u16* ldsW = ldsAll + 8192;

  const char* Xb = (const char*)(a.X[tower] + ((size_t)b * PA_TOTAL + base) * CCH);
  const char* Wb = (const char*)(a.Wt[tower]);       // full 256-row W matrix

  // BK=64 staging swizzle (R12): slot (row,col) holds k-chunk col ^ (row&7);
  // pre-folded into the per-lane GLOBAL byte offset qsw2; LDS dest linear.
  const int qsw2 = ((lane & 7) ^ (lane >> 3)) * 16;
  // X: 2 gloads per wave, g = wv + 8k covers rows 8g..8g+7.
  int xoffG[2];
  unsigned mask9[2];
  int xl[2];
#pragma unroll
  for (int k = 0; k < 2; ++k) {
    const int g = wv + 8 * k;
    const int prow = n0 + 8 * g + (lane >> 3);
    int rr = prow / W, cc = prow - rr * W;
    unsigned m = 0;
#pragma unroll
    for (int tap = 0; tap < 9; ++tap) {
      const int dh = tap / 3 - 1, dw = tap % 3 - 1;
      bool v = ((unsigned)(rr + dh) < (unsigned)H) & ((unsigned)(cc + dw) < (unsigned)W);
      m |= ((unsigned)v) << tap;
    }
    mask9[k] = m;
    xoffG[k] = prow * (CCH * 2) + qsw2;
    xl[k] = g * 1024;
  }
  const int padoff = P * (CCH * 2) + qsw2;   // zero pixel-padding row (halo target)
  // W: 4 gloads per wave, g = wv + 8k covers rows 8g..8g+7 (g 0..31 = 256 rows).
  int woffG[4], wl[4];
#pragma unroll
  for (int k = 0; k < 4; ++k) {
    const int g = wv + 8 * k;
    const int wrow = 8 * g + (lane >> 3);
    woffG[k] = wrow * (KTOT * 2) + qsw2;
    wl[k] = 16384 + g * 1024;                // byte offset within ldsAll
  }

  // fragment LDS offsets (u16), reader swizzle col = kq ^ (row&7);
  // h=1 offsets are h=0 ^ 32 elems (bit-2 of kq scaled by 8; no carry).
  const int arow = lane & 15, rsw = lane & 7, kq0 = lane >> 4;
  const int csw0 = (kq0 ^ rsw) * 8;
  int aoff[4], boff[4];
#pragma unroll
  for (int i = 0; i < 4; ++i) {
    aoff[i] = (wm * 64 + i * 16 + arow) * 64 + csw0;   // within 256-row W region
    boff[i] = (wn * 64 + i * 16 + arow) * 64 + csw0;
  }

  floatx4 acc[4][4];
#pragma unroll
  for (int i = 0; i < 4; ++i)
#pragma unroll
    for (int j = 0; j < 4; ++j) acc[i][j] = (floatx4)0.f;

  // K-loop: icb outer, taps inner (unrolled). Uniform step body; all staging
  // is async DMA, no staging registers, no ds_writes.
#pragma unroll 1
  for (int icb = 0; icb < 4; ++icb) {
#pragma unroll
    for (int tap = 0; tap < 9; ++tap) {
      __syncthreads();   // all waves done reading LDS of previous step
      const int ko = (tap * 256 + icb * 64) * 2;                 // W byte off, uniform
      const int dh = tap / 3 - 1, dw = tap % 3 - 1;
      const int doff = (dh * W + dw) * (CCH * 2) + icb * 128;    // X byte off, uniform
#pragma unroll
      for (int k = 0; k < 2; ++k) {
        const int off = ((mask9[k] >> tap) & 1u) ? (xoffG[k] + doff) : padoff;
        gload16(Xb + off, (char*)ldsAll + xl[k]);
      }
#pragma unroll
      for (int k = 0; k < 4; ++k)
        gload16(Wb + woffG[k] + ko, (char*)ldsAll + wl[k]);
      // all 6 gloads must land block-wide before MFMA reads LDS
      asm volatile("s_waitcnt vmcnt(0) lgkmcnt(0)\n\ts_barrier" ::: "memory");
      __builtin_amdgcn_s_setprio(1);
#pragma unroll
      for (int h = 0; h < 2; ++h) {
        const int hx = h * 32;
        short8 af[4], bv[4];
#pragma unroll
        for (int i = 0; i < 4; ++i) af[i] = *(const short8*)(ldsW + (aoff[i] ^ hx));
#pragma unroll
        for (int j = 0; j < 4; ++j) bv[j] = *(const short8*)(ldsX + (boff[j] ^ hx));
#pragma unroll
        for (int i = 0; i < 4; ++i)
#pragma unroll
          for (int j = 0; j < 4; ++j)
            acc[i][j] = __builtin_amdgcn_mfma_f32_16x16x32_bf16(af[i], bv[j], acc[i][j], 0, 0, 0);
      }
      __builtin_amdgcn_s_setprio(0);
    }
  }

  // epilogue; D[m=(lane>>4)*4+r][n=lane&15]; oc = wm*64 + i*16 + quad*4 + r
  const int quad = lane >> 4, col = lane & 15;
  u16* convB = a.outB[tower];
  float s[4] = {0.f, 0.f, 0.f, 0.f}, ss[4] = {0.f, 0.f, 0.f, 0.f};
#pragma unroll
  for (int j = 0; j < 4; ++j) {
    int pl = n0 + wn * 64 + j * 16 + col;
    bool valid = pl < P;
    u16* dst = convB + ((size_t)b * PA_TOTAL + base + pl) * CCH + wm * 64 + quad * 4;
#pragma unroll
    for (int i = 0; i < 4; ++i) {
      ushort4 hv;
#pragma unroll
      for (int r = 0; r < 4; ++r) {
        u16 hh = f2bf(acc[i][j][r]);
        ((u16*)&hv)[r] = hh;
        float vr = bf2f(hh);                    // accumulate ROUNDED value -> GN self-consistent
        if (valid) { s[i] += vr; ss[i] += vr * vr; }
      }
      if (valid) *(ushort4*)(dst + i * 16) = hv;
    }
  }
  // half-wave tree: lane0 sums lanes 0-31 (quads 0,1), lane32 sums 32-63 (quads 2,3)
#pragma unroll
  for (int i = 0; i < 4; ++i) {
#pragma unroll
    for (int off = 16; off >= 1; off >>= 1) {
      s[i] += __shfl_down(s[i], off, 64);
      ss[i] += __shfl_down(ss[i], off, 64);
    }
  }
  if ((lane & 31) == 0) {
    int half = lane >> 5;
#pragma unroll
    for (int i = 0; i < 4; ++i) {
      float* st = a.stats + tower * 640 +
                  ((size_t)((b * 5 + lvl) * 32 + wm * 8 + i * 2 + half)) * 2;
      atomicAdd(st, s[i]);
      atomicAdd(st + 1, ss[i]);
    }
  }
}

// ---- PRED convs (R12's proven body, unchanged): 32oc x 128px tiles,
// single-buffer DMA staging, vmcnt(0) per step. grid (108,2,2).
__global__ __launch_bounds__(256) void conv_pred(ConvArgs a, Tables tb) {
  constexpr int NI = 1;
  constexpr int WROWS = 32;
  const int L = blockIdx.x + 108 * (blockIdx.y + 2 * blockIdx.z);
  const int xcd = L & 7, slot = L >> 3;
  const int tower = xcd >> 2, b = (xcd >> 1) & 1;
  const int t = slot * 2 + (xcd & 1);
  if (t >= 107) return;
  int lvl = 0;
#pragma unroll
  for (int i = 1; i < 5; ++i) if (t >= tb.tile0[i]) lvl = i;
  const int H = tb.H[lvl], W = tb.W[lvl], P = tb.P[lvl], base = tb.base[lvl];
  const int n0 = (t - tb.tile0[lvl]) * 128;

  const int tid = threadIdx.x;
  const int lane = tid & 63, wv = tid >> 6;
  const int wm = wv >> 1, wn = wv & 1;

  __shared__ u16 ldsAll[128 * 64 + WROWS * 64];
  u16* ldsX = ldsAll;
  u16* ldsW = ldsAll + 128 * 64;

  const char* Xb = (const char*)(a.X[tower] + ((size_t)b * PA_TOTAL + base) * CCH);
  const char* Wb = (const char*)(a.Wt[tower]);

  const int qsw2 = ((lane & 7) ^ (lane >> 3)) * 16;
  int xoffG[4];
  unsigned mask9[4];
  int xlds[4];
#pragma unroll
  for (int t4 = 0; t4 < 4; ++t4) {
    int row = (t4 * 4 + wv) * 8 + (lane >> 3);
    int prow = n0 + row;
    int rr = prow / W, cc = prow - rr * W;
    unsigned m = 0;
#pragma unroll
    for (int tap = 0; tap < 9; ++tap) {
      const int dh = tap / 3 - 1, dw = tap % 3 - 1;
      bool v = ((unsigned)(rr + dh) < (unsigned)H) & ((unsigned)(cc + dw) < (unsigned)W);
      m |= ((unsigned)v) << tap;
    }
    mask9[t4] = m;
    xoffG[t4] = prow * (CCH * 2) + qsw2;
    xlds[t4] = (t4 * 4 + wv) * 1024;
  }
  const int padoff = P * (CCH * 2) + qsw2;
  int woffG[NI];
  int wlds[NI];
#pragma unroll
  for (int e = 0; e < NI; ++e) {
    int wrow = wv * 8 + (lane >> 3);
    woffG[e] = wrow * (KTOT * 2) + qsw2;
    wlds[e] = 16384 + wv * 1024;
  }

  const int arow = lane & 15, rsw = lane & 7, kq0 = lane >> 4;
  const int csw0 = (kq0 ^ rsw) * 8;
  int aoff[NI], boff[4];
#pragma unroll
  for (int i = 0; i < NI; ++i) aoff[i] = (wm * 16 + arow) * 64 + csw0;
#pragma unroll
  for (int i = 0; i < 4; ++i) boff[i] = (wn * 64 + i * 16 + arow) * 64 + csw0;

  floatx4 acc[NI][4];
#pragma unroll
  for (int i = 0; i < NI; ++i)
#pragma unroll
    for (int j = 0; j < 4; ++j) acc[i][j] = (floatx4)0.f;

#pragma unroll 1
  for (int icb = 0; icb < 4; ++icb) {
#pragma unroll
    for (int tap = 0; tap < 9; ++tap) {
      __syncthreads();
      const int ko = (tap * 256 + icb * 64) * 2;
      const int dh = tap / 3 - 1, dw = tap % 3 - 1;
      const int doff = (dh * W + dw) * (CCH * 2) + icb * 128;
#pragma unroll
      for (int t4 = 0; t4 < 4; ++t4) {
        const int off = ((mask9[t4] >> tap) & 1u) ? (xoffG[t4] + doff) : padoff;
        gload16(Xb + off, (char*)ldsAll + xlds[t4]);
      }
#pragma unroll
      for (int e = 0; e < NI; ++e)
        gload16(Wb + woffG[e] + ko, (char*)ldsAll + wlds[e]);
      asm volatile("s_waitcnt vmcnt(0) lgkmcnt(0)\n\ts_barrier" ::: "memory");
      __builtin_amdgcn_s_setprio(1);
#pragma unroll
      for (int h = 0; h < 2; ++h) {
        const int hx = h * 32;
        short8 af[NI], bv[4];
#pragma unroll
        for (int i = 0; i < NI; ++i) af[i] = *(const short8*)(ldsW + (aoff[i] ^ hx));
#pragma unroll
        for (int j = 0; j < 4; ++j) bv[j] = *(const short8*)(ldsX + (boff[j] ^ hx));
#pragma unroll
        for (int i = 0; i < NI; ++i)
#pragma unroll
          for (int j = 0; j < 4; ++j)
            acc[i][j] = __builtin_amdgcn_mfma_f32_16x16x32_bf16(af[i], bv[j], acc[i][j], 0, 0, 0);
      }
      __builtin_amdgcn_s_setprio(0);
    }
  }

  const int quad = lane >> 4, col = lane & 15;
  float* dout = a.dout;
  if (tower == 0) {
#pragma unroll
    for (int j = 0; j < 4; ++j) {
      int pl = n0 + wn * 64 + j * 16 + col;
      if (pl >= P) continue;
      int ocb = wm * 16 + quad * 4;
#pragma unroll
      for (int r = 0; r < 4; ++r) {
        int oc = ocb + r;
        float v = acc[0][j][r];
        if (oc < 20)       dout[tb.lb[lvl] + ((size_t)b * 20 + oc) * P + pl] = v + a.biasCls[oc];
        else if (oc == 20) dout[tb.cb[lvl] + (size_t)b * P + pl] = v + a.biasCtr[0];
      }
    }
  } else {
    float sc = a.scales[lvl];
#pragma unroll
    for (int j = 0; j < 4; ++j) {
      int pl = n0 + wn * 64 + j * 16 + col;
      if (pl >= P) continue;
      int ocb = wm * 16 + quad * 4;
#pragma unroll
      for (int r = 0; r < 4; ++r) {
        int oc = ocb + r;
        if (oc < 4)
          dout[tb.bb[lvl] + ((size_t)b * 4 + oc) * P + pl] = expf((acc[0][j][r] + a.biasBox[oc]) * sc);
      }
    }
  }
}

// ---- GroupNorm pass 2: normalize + affine + ReLU, bf16 -> bf16, coalesced; both towers.
// grid (3424, 2): y = tower. Pixel-padding rows ZEROED (conv halo redirect target).
__global__ void gn_norm(const u16* __restrict__ c0, const u16* __restrict__ c1,
                        const float* __restrict__ stats,
                        const float* __restrict__ g0, const float* __restrict__ b0,
                        const float* __restrict__ g1, const float* __restrict__ b1,
                        u16* __restrict__ a0, u16* __restrict__ a1, Tables tb) {
  const int tower = blockIdx.y;
  const u16* convB = tower ? c1 : c0;
  const float* gamma = tower ? g1 : g0;
  const float* beta = tower ? b1 : b0;
  u16* act = tower ? a1 : a0;
  int idx = blockIdx.x * 256 + threadIdx.x;
  int c8 = idx & 31;                 // == group index
  int rest = idx >> 5;
  int p = rest % PA_TOTAL;
  int b = rest / PA_TOTAL;
  int lvl = 0;
#pragma unroll
  for (int i = 1; i < 5; ++i) if (p >= tb.base[i]) lvl = i;
  if (p - tb.base[lvl] >= tb.P[lvl]) {
    short8 z = (short8)(short)0;
    *(short8*)(act + ((size_t)b * PA_TOTAL + p) * CCH + c8 * 8) = z;
    return;
  }
  const float* st = stats + tower * 640 + ((size_t)((b * 5 + lvl) * 32 + c8)) * 2;
  float cnt = 8.f * (float)tb.P[lvl];
  float mean = st[0] / cnt;
  float var = st[1] / cnt - mean * mean;
  float inv = rsqrtf(var + 1e-5f);
  const short8 x = *(const short8*)(convB + ((size_t)b * PA_TOTAL + p) * CCH + c8 * 8);
  short8 o;
#pragma unroll
  for (int j = 0; j < 8; ++j) {
    float v = bf2f((u16)x[j]);
    float y = (v - mean) * inv * gamma[c8 * 8 + j] + beta[c8 * 8 + j];
    y = fmaxf(y, 0.f);
    o[j] = (short)f2bf(y);
  }
  *(short8*)(act + ((size_t)b * PA_TOTAL + p) * CCH + c8 * 8) = o;
}

extern "C" void kernel_launch(void* const* d_in, const int* in_sizes, int n_in,
                              void* d_out, int out_size, void* d_ws, size_t ws_size,
                              hipStream_t stream) {
  const float* feat[5];
  for (int i = 0; i < 5; ++i) feat[i] = (const float*)d_in[i];
  const float* cls_tw_w  = (const float*)d_in[5];
  const float* cls_tw_g  = (const float*)d_in[6];
  const float* cls_tw_b  = (const float*)d_in[7];
  const float* box_tw_w  = (const float*)d_in[8];
  const float* box_tw_g  = (const float*)d_in[9];
  const float* box_tw_b  = (const float*)d_in[10];
  const float* cls_pred_w = (const float*)d_in[11];
  const float* cls_pred_b = (const float*)d_in[12];
  const float* box_pred_w = (const float*)d_in[13];
  const float* box_pred_b = (const float*)d_in[14];
  const float* ctr_pred_w = (const float*)d_in[15];
  const float* ctr_pred_b = (const float*)d_in[16];
  const float* scales     = (const float*)d_in[17];
  float* out = (float*)d_out;

  char* ws = (char*)d_ws;
  float* statsAll = (float*)(ws);                    // 4 stages x 1280 floats = 20480 B
  u16*   WrCls  = (u16*)(ws + 24576);                // 1024 x 2304 bf16
  u16*   WrBox  = (u16*)(ws + 24576 + 4718592);
  u16*   WrPCls = (u16*)(ws + 24576 + 2 * 4718592);              // 32 x 2304 (21 used)
  u16*   WrPBox = (u16*)(ws + 24576 + 2 * 4718592 + 147456);     // 32 x 2304 (4 used)
  u16*   bufIn   = (u16*)(ws + 10625024);
  u16*   bufAct0 = (u16*)(ws + 10625024 + 1 * (size_t)14024704);
  u16*   bufAct1 = (u16*)(ws + 10625024 + 2 * (size_t)14024704);
  u16*   bufCv0  = (u16*)(ws + 10625024 + 3 * (size_t)14024704);
  u16*   bufCv1  = (u16*)(ws + 10625024 + 4 * (size_t)14024704);

  // 128-px tiling: tile0 {0,79,99,104,106}, 107 tiles
  Tables tb = { {100,50,25,13,7}, {100,50,25,13,7}, {10000,2500,625,169,49},
                {0,10112,12672,13312,13568}, {0,79,99,104,106},
                {0,400000,500000,525000,531760},
                {533720,613720,633720,638720,640072},
                {640464,660464,665464,666714,667052} };

  // one upfront memset for all 4 stages' stats
  hipMemsetAsync(statsAll, 0, 20480, stream);

  ReorderArgs ra = { cls_tw_w, box_tw_w, cls_pred_w, ctr_pred_w, box_pred_w,
                     WrCls, WrBox, WrPCls, WrPBox };
  reorder_all<<<2112, 256, 0, stream>>>(ra);

  FeatPtrs fp = {{feat[0], feat[1], feat[2], feat[3], feat[4]}};
  convert_inputs<<<dim3(PA_TOTAL / 32, 8, 2), 256, 0, stream>>>(fp, bufIn, tb);

  ConvArgs a;
  a.dout = out;
  a.biasCls = cls_pred_b; a.biasCtr = ctr_pred_b; a.biasBox = box_pred_b; a.scales = scales;
  a.outB[0] = bufCv0; a.outB[1] = bufCv1;

  for (int s = 0; s < 4; ++s) {
    a.X[0] = (s == 0) ? bufIn : bufAct0;
    a.X[1] = (s == 0) ? bufIn : bufAct1;
    a.Wt[0] = WrCls + (size_t)s * 256 * KTOT;
    a.Wt[1] = WrBox + (size_t)s * 256 * KTOT;
    a.stats = statsAll + (size_t)s * 1280;
    conv_tower<<<dim3(107, 2, 2), 512, 0, stream>>>(a, tb);
    gn_norm<<<dim3(3424, 2), 256, 0, stream>>>(bufCv0, bufCv1, a.stats,
                                               cls_tw_g + s * 256, cls_tw_b + s * 256,
                                               box_tw_g + s * 256, box_tw_b + s * 256,
                                               bufAct0, bufAct1, tb);
  }
  a.X[0] = bufAct0; a.X[1] = bufAct1;
  a.Wt[0] = WrPCls; a.Wt[1] = WrPBox;
  conv_pred<<<dim3(108, 2, 2), 256, 0, stream>>>(a, tb);
}